// Round 6
// baseline (146.513 us; speedup 1.0000x reference)
//
#include <hip/hip_runtime.h>

#define D      256
#define NROWS  8192
#define BHALF  4096
#define TILE   128
#define NT2    (NROWS / TILE)          // 64
#define NBLK   (NT2 * (NT2 + 1) / 2)   // 2080
#define NGRID  512                      // 2 blocks/CU (64 KB LDS each)
#define NBINS  64

typedef __attribute__((ext_vector_type(8))) short  short8;
typedef __attribute__((ext_vector_type(4))) float  f32x4;

// ws layout (memset zeroes [0..2048)):
//   0     double sumsq
//   8     unsigned counter
//   16    double bins[64]          -> ends 528
//   1024  float colsum[256]        -> ends 2048
//   4096  float sq[8192]           -> ends 36864
//   36864 bf16 Tb[8192][256] (4 MB) -> ends 4231168 (proven < ws_size)

__device__ __forceinline__ unsigned short f2bf(float f) {
    unsigned u = __builtin_bit_cast(unsigned, f);
    unsigned r = (u + 0x7fffu + ((u >> 16) & 1u)) >> 16;   // RNE (no NaN in data)
    return (unsigned short)r;
}

__device__ __forceinline__ void gload_lds16(const unsigned short* g, unsigned short* l) {
    __builtin_amdgcn_global_load_lds(
        (const __attribute__((address_space(1))) unsigned int*)g,
        (__attribute__((address_space(3))) unsigned int*)l,
        16, 0, 0);
}

// ---------------------------------------------------------------- pass 1
__global__ __launch_bounds__(256)
void pre_kernel(const float* __restrict__ src, const float* __restrict__ tar,
                float* __restrict__ sq, float* __restrict__ colsum,
                double* __restrict__ sumsq, unsigned short* __restrict__ Tb) {
    __shared__ float cs[D];
    int t = threadIdx.x;
    cs[t] = 0.f;
    __syncthreads();

    int lane = t & 63, w = t >> 6;
    int rowBase = blockIdx.x * 32 + w * 8;

    float4 v[8];
    #pragma unroll
    for (int it = 0; it < 8; ++it) {
        int r = rowBase + it;
        const float* rowp = (r < BHALF) ? (src + (size_t)r * D)
                                        : (tar + (size_t)(r - BHALF) * D);
        v[it] = *(const float4*)(rowp + lane * 4);
    }

    float4 csum = make_float4(0.f, 0.f, 0.f, 0.f);
    float sqacc = 0.f;
    #pragma unroll
    for (int it = 0; it < 8; ++it) {
        int r = rowBase + it;
        ushort4 h;
        h.x = f2bf(v[it].x); h.y = f2bf(v[it].y);
        h.z = f2bf(v[it].z); h.w = f2bf(v[it].w);
        *(ushort4*)(Tb + (size_t)r * D + lane * 4) = h;
        csum.x += v[it].x; csum.y += v[it].y; csum.z += v[it].z; csum.w += v[it].w;
        float s = v[it].x * v[it].x + v[it].y * v[it].y +
                  v[it].z * v[it].z + v[it].w * v[it].w;
        #pragma unroll
        for (int off = 32; off; off >>= 1) s += __shfl_xor(s, off, 64);
        if (lane == 0) { sq[r] = s; sqacc += s; }
    }
    atomicAdd(&cs[lane * 4 + 0], csum.x);
    atomicAdd(&cs[lane * 4 + 1], csum.y);
    atomicAdd(&cs[lane * 4 + 2], csum.z);
    atomicAdd(&cs[lane * 4 + 3], csum.w);
    if (lane == 0) atomicAdd(sumsq, (double)sqacc);
    __syncthreads();
    atomicAdd(&colsum[t], cs[t]);
}

// ---------------------------------------------------------------- main (persistent)
__global__ __launch_bounds__(256, 2)
void mmd_main(const unsigned short* __restrict__ Tb,
              const float* __restrict__ sq, const float* __restrict__ colsum,
              const double* __restrict__ sumsq,
              double* __restrict__ bins, unsigned* __restrict__ counter,
              float* __restrict__ out)
{
    __shared__ unsigned short As[TILE * D];   // 64 KB: full-K A panel only

    int t = threadIdx.x, lane = t & 63, wid = t >> 6;
    int wi = wid >> 1, wj = wid & 1;
    int lr = lane & 15, lk = lane >> 4;

    // XCD-contiguous pair runs (512 % 8 == 0, bijective)
    int bid = blockIdx.x;
    int sw = (bid & 7) * (NGRID / 8) + (bid >> 3);
    int pstart = (int)(((long)sw * NBLK) / NGRID);
    int pend   = (int)(((long)(sw + 1) * NBLK) / NGRID);

    int ti, tj;
    {
        int rem = pstart, a = 0;
        while (rem >= NT2 - a) { rem -= NT2 - a; ++a; }
        ti = a; tj = a + rem;
    }

    // A staging: LDS linear [row][chunk], global chunk pre-swizzled c^(row&7)
    auto stageA = [&](int tt) {
        const unsigned short* g = Tb + (size_t)tt * TILE * D;
        #pragma unroll
        for (int p = 0; p < 16; ++p) {
            int q = p * 256 + t;           // 16B-chunk id, 0..4095
            int row = q >> 5, c = q & 31;
            gload_lds16(g + row * D + ((c ^ (row & 7)) << 3), &As[q << 3]);
        }
    };

    stageA(ti);

    // bandwidth -> g2, computed redundantly per block (overlaps A stage)
    float4 c4 = *(const float4*)(colsum + lane * 4);
    float s = c4.x * c4.x + c4.y * c4.y + c4.z * c4.z + c4.w * c4.w;
    #pragma unroll
    for (int off = 32; off; off >>= 1) s += __shfl_xor(s, off, 64);
    double sumL2 = 2.0 * (double)NROWS * (*sumsq) - 2.0 * (double)s;
    double bwd = sumL2 / ((double)NROWS * (double)NROWS - (double)NROWS) / 4.0;
    float g2 = (float)(1.4426950408889634 / (16.0 * bwd));

    asm volatile("s_waitcnt vmcnt(0)" ::: "memory");
    __syncthreads();                           // A panel ready

    for (int p = pstart; p < pend; ++p) {
        int rowA = ti * TILE + wi * 64, rowB = tj * TILE + wj * 64;
        const unsigned short* gB = Tb + (size_t)rowB * D;   // wave's B band

        float sqj[4], sqi[4][4];
        #pragma unroll
        for (int n = 0; n < 4; ++n) sqj[n] = sq[rowB + n * 16 + lr];
        #pragma unroll
        for (int m = 0; m < 4; ++m)
            #pragma unroll
            for (int r = 0; r < 4; ++r)
                sqi[m][r] = sq[rowA + m * 16 + lk * 4 + r];

        f32x4 acc[4][4];
        #pragma unroll
        for (int m = 0; m < 4; ++m)
            #pragma unroll
            for (int n = 0; n < 4; ++n)
                acc[m][n] = (f32x4){0.f, 0.f, 0.f, 0.f};

        // full-K sweep: A from LDS, B streamed from L2 into registers.
        // No barriers — waves drift independently across pairs.
        #pragma unroll
        for (int ks = 0; ks < 8; ++ks) {
            short8 a[4], b[4];
            int ca = ks * 4 + lk;
            #pragma unroll
            for (int m = 0; m < 4; ++m) {
                int rA = wi * 64 + m * 16 + lr;
                a[m] = *(const short8*)&As[rA * D + ((ca ^ (rA & 7)) << 3)];
                b[m] = *(const short8*)(gB + (size_t)(m * 16 + lr) * D + ca * 8);
            }
            #pragma unroll
            for (int m = 0; m < 4; ++m)
                #pragma unroll
                for (int n = 0; n < 4; ++n)
                    acc[m][n] = __builtin_amdgcn_mfma_f32_16x16x32_bf16(
                                    a[m], b[n], acc[m][n], 0, 0, 0);
        }

        // epilogue: L2 -> u + u^2 + u^4 + u^8 + u^16 -> signed bin add
        float local = 0.f;
        #pragma unroll
        for (int m = 0; m < 4; ++m) {
            #pragma unroll
            for (int r = 0; r < 4; ++r) {
                float si = sqi[m][r];
                #pragma unroll
                for (int n = 0; n < 4; ++n) {
                    float L2 = fmaxf(si + sqj[n] - 2.f * acc[m][n][r], 0.f);
                    float u = exp2f(-L2 * g2);
                    float u2 = u * u, u4 = u2 * u2, u8 = u4 * u4, u16 = u8 * u8;
                    local += u + u2 + u4 + u8 + u16;
                }
            }
        }
        #pragma unroll
        for (int off = 32; off; off >>= 1) local += __shfl_xor(local, off, 64);
        if (lane == 0) {
            float scale = ((ti < NT2 / 2) == (tj < NT2 / 2)) ? 1.f : -1.f;
            if (ti != tj) scale *= 2.f;
            atomicAdd(&bins[((sw << 2) + wid) & (NBINS - 1)],
                      (double)(scale * local));
        }

        // advance; restage A only when the tile-row changes
        int nti = ti, ntj = tj + 1;
        if (ntj >= NT2) { nti = ti + 1; ntj = nti; }
        if (p + 1 < pend && nti != ti) {
            __syncthreads();                   // all waves done reading As
            stageA(nti);
            asm volatile("s_waitcnt vmcnt(0)" ::: "memory");
            __syncthreads();
        }
        ti = nti; tj = ntj;
    }

    __syncthreads();
    if (t == 0) {
        __threadfence();
        unsigned old = atomicAdd(counter, 1u);
        if (old == NGRID - 1) {                // last block finalizes
            __threadfence();
            double tot = 0.0;
            for (int i = 0; i < NBINS; ++i)
                tot += ((volatile double*)bins)[i];
            out[0] = (float)(tot / ((double)BHALF * (double)BHALF));
        }
    }
}

extern "C" void kernel_launch(void* const* d_in, const int* in_sizes, int n_in,
                              void* d_out, int out_size, void* d_ws, size_t ws_size,
                              hipStream_t stream) {
    const float* src = (const float*)d_in[0];
    const float* tar = (const float*)d_in[1];
    float* out = (float*)d_out;

    char* ws = (char*)d_ws;
    double*   sumsq   = (double*)(ws + 0);
    unsigned* counter = (unsigned*)(ws + 8);
    double*   bins    = (double*)(ws + 16);
    float*    colsum  = (float*)(ws + 1024);
    float*    sq      = (float*)(ws + 4096);
    unsigned short* Tb = (unsigned short*)(ws + 36864);

    hipMemsetAsync(ws, 0, 2048, stream);
    pre_kernel<<<256, 256, 0, stream>>>(src, tar, sq, colsum, sumsq, Tb);
    mmd_main<<<NGRID, 256, 0, stream>>>(Tb, sq, colsum, sumsq, bins, counter, out);
}